// Round 16
// baseline (50.433 us; speedup 1.0000x reference)
//
#include <hip/hip_runtime.h>
#include <math.h>

#define NROWS 8192
#define NK    4096
#define NE    64
#define NKS   32     // k-steps of 32 per wave (K-seg 1024)

typedef _Float16 f16x8 __attribute__((ext_vector_type(8)));
typedef float    f32x4 __attribute__((ext_vector_type(4)));

#define CVT8(H, L, V0, V1)                                            \
  do {                                                                \
    H[0] = (_Float16)V0.x; L[0] = (_Float16)(V0.x - (float)H[0]);     \
    H[1] = (_Float16)V0.y; L[1] = (_Float16)(V0.y - (float)H[1]);     \
    H[2] = (_Float16)V0.z; L[2] = (_Float16)(V0.z - (float)H[2]);     \
    H[3] = (_Float16)V0.w; L[3] = (_Float16)(V0.w - (float)H[3]);     \
    H[4] = (_Float16)V1.x; L[4] = (_Float16)(V1.x - (float)H[4]);     \
    H[5] = (_Float16)V1.y; L[5] = (_Float16)(V1.y - (float)H[5]);     \
    H[6] = (_Float16)V1.z; L[6] = (_Float16)(V1.z - (float)H[6]);     \
    H[7] = (_Float16)V1.w; L[7] = (_Float16)(V1.w - (float)H[7]);     \
  } while (0)

__device__ __forceinline__ void gload16(const void* g, void* l) {
  __builtin_amdgcn_global_load_lds(
      (const __attribute__((address_space(1))) unsigned int*)g,
      (__attribute__((address_space(3))) unsigned int*)l, 16, 0, 0);
}

// ---------------------------------------------------------------------------
// Kernel 0: W -> MFMA-fragment-linear f16 hi/lo (verified rounds 4-15); zero
// imp + completion counter. Element ((gk*4 + nt)*64 + lane)*8 + j holds
//   f16( W[nt*16 + (lane&15)][gk*32 + (lane>>4)*8 + j] ), gk = 0..127.
// ---------------------------------------------------------------------------
__global__ __launch_bounds__(256) void k_prep(const float* __restrict__ W,
                                              _Float16* __restrict__ Whi,
                                              _Float16* __restrict__ Wlo,
                                              float* __restrict__ imp,
                                              unsigned* __restrict__ cnt) {
  const int idx = blockIdx.x * 256 + threadIdx.x;   // 0 .. 262143
  if (idx < NE) imp[idx] = 0.f;
  if (idx == NE) *cnt = 0u;
  const int j    = idx & 7;
  const int lane = (idx >> 3) & 63;
  const int nt   = (idx >> 9) & 3;
  const int gk   = idx >> 11;                        // 0..127
  const int e = nt * 16 + (lane & 15);
  const int k = gk * 32 + (lane >> 4) * 8 + j;
  const float w = W[(size_t)e * NK + k];
  const _Float16 wh = (_Float16)w;
  const _Float16 wl = (_Float16)(w - (float)wh);
  Whi[idx] = wh;
  Wlo[idx] = wl;
}

// ---------------------------------------------------------------------------
// Kernel 1 (FUSED, wave-private pipeline): grid = 256 (1 block/CU), block =
// 256 (4 waves). Wave wv = 32 rows x 64 experts x K-seg 1024, staging its
// own x+W chunks via global_load_lds into a PRIVATE 36 KB LDS region
// (3 slots x 12 KB). Because each wave reads only LDS it staged itself,
// per-wave counted vmcnt is valid (r12's cross-wave flaw fixed) -> NO block
// barriers in the k-loop; 3-deep pipeline keeps 24 KB/wave (96 KB/CU) in
// flight >> 22 KB BDP. gload_lds has no VGPR dest -> the allocator cannot
// serialize staging (r7-r15's failure mode).
// Slot layout (12 KB): [0,4K) x-frags [mi][half][lane]f4; [4K,8K) W-hi
// [nt][lane]f16x8; [8K,12K) W-lo. Mappings byte-identical to r14 (absmax 0).
// ---------------------------------------------------------------------------
__global__ __launch_bounds__(256, 1) void k_fused(const float* __restrict__ x,
                                                  const _Float16* __restrict__ Whi,
                                                  const _Float16* __restrict__ Wlo,
                                                  float* __restrict__ out,
                                                  float* __restrict__ imp,
                                                  unsigned* __restrict__ cnt) {
  __shared__ char LDS[4 * 3 * 12288];   // 144 KB: 4 wave-regions x 3 slots
  __shared__ int lastflag;

  const int tid  = threadIdx.x;
  const int lane = tid & 63;
  const int wv   = __builtin_amdgcn_readfirstlane(tid >> 6);  // 0..3 = K-seg
  const int l15  = lane & 15;
  const int lhi  = lane >> 4;
  const int rb   = blockIdx.x * 32;
  const int k0   = wv * 1024;

  char* const region = LDS + wv * 36864;

  // per-lane global sources (g: mi = g>>1, half = g&1)
  const float* xsrc0 = x + (size_t)(rb + 0  + l15) * NK + k0 + lhi * 8 + 0;
  const float* xsrc1 = x + (size_t)(rb + 0  + l15) * NK + k0 + lhi * 8 + 4;
  const float* xsrc2 = x + (size_t)(rb + 16 + l15) * NK + k0 + lhi * 8 + 0;
  const float* xsrc3 = x + (size_t)(rb + 16 + l15) * NK + k0 + lhi * 8 + 4;
  const _Float16* whsrc = Whi + ((size_t)(wv * 32 * 4) * 64 + lane) * 8;
  const _Float16* wlsrc = Wlo + ((size_t)(wv * 32 * 4) * 64 + lane) * 8;

#define STAGE(ks, sl)                                                         \
  do {                                                                        \
    char* slot_ = region + (sl) * 12288;                                      \
    gload16(xsrc0 + (size_t)(ks) * 32, slot_ + 0 * 1024);                     \
    gload16(xsrc1 + (size_t)(ks) * 32, slot_ + 1 * 1024);                     \
    gload16(xsrc2 + (size_t)(ks) * 32, slot_ + 2 * 1024);                     \
    gload16(xsrc3 + (size_t)(ks) * 32, slot_ + 3 * 1024);                     \
    _Pragma("unroll")                                                         \
    for (int g = 0; g < 4; ++g)                                               \
      gload16(whsrc + (size_t)(ks) * 2048 + g * 512, slot_ + 4096 + g * 1024);\
    _Pragma("unroll")                                                         \
    for (int g = 0; g < 4; ++g)                                               \
      gload16(wlsrc + (size_t)(ks) * 2048 + g * 512, slot_ + 8192 + g * 1024);\
  } while (0)

  // load fragments from slot sl, then 24 MFMAs (r14-verified mappings)
#define STEP(sl)                                                              \
  do {                                                                        \
    char* slot_ = region + (sl) * 12288;                                      \
    const float4 xa0 = *(const float4*)(slot_ + ((0 * 64 + lane) * 16));      \
    const float4 xa1 = *(const float4*)(slot_ + ((1 * 64 + lane) * 16));      \
    const float4 xb0 = *(const float4*)(slot_ + ((2 * 64 + lane) * 16));      \
    const float4 xb1 = *(const float4*)(slot_ + ((3 * 64 + lane) * 16));      \
    f16x8 wh_[4], wl_[4];                                                     \
    _Pragma("unroll")                                                         \
    for (int nt = 0; nt < 4; ++nt) {                                          \
      wh_[nt] = *(const f16x8*)(slot_ + 4096 + (nt * 64 + lane) * 16);        \
      wl_[nt] = *(const f16x8*)(slot_ + 8192 + (nt * 64 + lane) * 16);        \
    }                                                                         \
    f16x8 ah, al, bh, bl;                                                     \
    CVT8(ah, al, xa0, xa1);                                                   \
    CVT8(bh, bl, xb0, xb1);                                                   \
    _Pragma("unroll")                                                         \
    for (int nt = 0; nt < 4; ++nt) {                                          \
      acc0[nt] = __builtin_amdgcn_mfma_f32_16x16x32_f16(ah, wh_[nt], acc0[nt], 0, 0, 0); \
      acc1[nt] = __builtin_amdgcn_mfma_f32_16x16x32_f16(bh, wh_[nt], acc1[nt], 0, 0, 0); \
    }                                                                         \
    _Pragma("unroll")                                                         \
    for (int nt = 0; nt < 4; ++nt) {                                          \
      acc0[nt] = __builtin_amdgcn_mfma_f32_16x16x32_f16(ah, wl_[nt], acc0[nt], 0, 0, 0); \
      acc1[nt] = __builtin_amdgcn_mfma_f32_16x16x32_f16(bh, wl_[nt], acc1[nt], 0, 0, 0); \
    }                                                                         \
    _Pragma("unroll")                                                         \
    for (int nt = 0; nt < 4; ++nt) {                                          \
      acc0[nt] = __builtin_amdgcn_mfma_f32_16x16x32_f16(al, wh_[nt], acc0[nt], 0, 0, 0); \
      acc1[nt] = __builtin_amdgcn_mfma_f32_16x16x32_f16(bl, wh_[nt], acc1[nt], 0, 0, 0); \
    }                                                                         \
  } while (0)

  f32x4 acc0[4], acc1[4];
#pragma unroll
  for (int nt = 0; nt < 4; ++nt) {
    acc0[nt] = (f32x4){0.f, 0.f, 0.f, 0.f};
    acc1[nt] = (f32x4){0.f, 0.f, 0.f, 0.f};
  }

  // ---- prologue: 3 chunks in flight (36 loads) ----
  STAGE(0, 0);
  STAGE(1, 1);
  STAGE(2, 2);

  int slidx = 0;
#pragma unroll 1
  for (int ks = 0; ks < NKS - 3; ++ks) {        // ks = 0..28
    asm volatile("s_waitcnt vmcnt(24)" ::: "memory");  // stage(ks) landed
    const int sl = slidx;
    // frag reads pinned between the two waitcnts (memory ops + clobbers)
    STEP(sl);
    asm volatile("s_waitcnt lgkmcnt(0)" ::: "memory"); // slot reads complete
    STAGE(ks + 3, sl);                                  // overwrite same slot
    slidx = (slidx == 2) ? 0 : slidx + 1;
  }
  // ---- peeled tail: vmcnt 24 -> 12 -> 0, no more staging ----
  asm volatile("s_waitcnt vmcnt(24)" ::: "memory");
  STEP(2);                                       // ks = 29 (29%3 == 2)
  asm volatile("s_waitcnt vmcnt(12)" ::: "memory");
  STEP(0);                                       // ks = 30
  asm volatile("s_waitcnt vmcnt(0)" ::: "memory");
  STEP(1);                                       // ks = 31

  // ---- partials into own region (bytes 0..8K), then block reduce ----
  {
    float* pl = (float*)region;                  // [32][64]
#pragma unroll
    for (int nt = 0; nt < 4; ++nt)
#pragma unroll
      for (int r = 0; r < 4; ++r) {
        pl[(lhi * 4 + r) * 64 + nt * 16 + l15]        = acc0[nt][r];
        pl[(16 + lhi * 4 + r) * 64 + nt * 16 + l15]   = acc1[nt][r];
      }
  }
  __syncthreads();

  float* logitp = (float*)(LDS + 12288);         // dead slot1 of region 0
  float* simpp  = (float*)(LDS + 20480);         // [4][64]
#pragma unroll
  for (int e = 0; e < 8; ++e) {
    const int elem = e * 256 + tid;              // 0..2047
    const int row  = elem >> 6;
    const int col  = elem & 63;
    const int off  = (row * 64 + col) * 4;
    const float v0 = *(const float*)(LDS + 0 * 36864 + off);
    const float v1 = *(const float*)(LDS + 1 * 36864 + off);
    const float v2 = *(const float*)(LDS + 2 * 36864 + off);
    const float v3 = *(const float*)(LDS + 3 * 36864 + off);
    logitp[row * 64 + col] = (v0 + v1) + (v2 + v3);
  }
  __syncthreads();

  // ---- softmax/top-2/renorm (verified r6-r15): wave wv rows wv*8..+8 ----
  float impacc = 0.f;
#pragma unroll 1
  for (int i = 0; i < 8; ++i) {
    const int rl  = wv * 8 + i;
    const int row = rb + rl;
    const float lg = logitp[rl * 64 + lane];

    float m = lg;
#pragma unroll
    for (int d = 1; d < 64; d <<= 1) m = fmaxf(m, __shfl_xor(m, d));
    float p = expf(lg - m);
    float s = p;
#pragma unroll
    for (int d = 1; d < 64; d <<= 1) s += __shfl_xor(s, d);
    const float gate = p / s;
    impacc += gate;

    const unsigned long long key =
        ((unsigned long long)__float_as_uint(gate) << 32) | (unsigned)(63 - lane);
    unsigned long long k1 = key;
#pragma unroll
    for (int d = 1; d < 64; d <<= 1) {
      unsigned long long o = __shfl_xor(k1, d);
      if (o > k1) k1 = o;
    }
    const int e1 = 63 - (int)(k1 & 63ull);
    unsigned long long k2 = (lane == e1) ? 0ull : key;
#pragma unroll
    for (int d = 1; d < 64; d <<= 1) {
      unsigned long long o = __shfl_xor(k2, d);
      if (o > k2) k2 = o;
    }
    const int e2 = 63 - (int)(k2 & 63ull);

    if (lane == 0) {
      const float g1 = __uint_as_float((unsigned)(k1 >> 32));
      const float g2 = __uint_as_float((unsigned)(k2 >> 32));
      const float tt  = expf(g2 - g1);          // g1 >= g2
      const float inv = 1.f / (1.f + tt);
      out[(size_t)row * 2]     = inv;
      out[(size_t)row * 2 + 1] = tt * inv;
      out[(size_t)NROWS * 2 + row * 2]     = (float)e1;
      out[(size_t)NROWS * 2 + row * 2 + 1] = (float)e2;
    }
  }
  simpp[wv * 64 + lane] = impacc;
  __syncthreads();

  // ---- importance atomics + last-block aux (verified r12/r14) ----
  if (tid < NE) {
    const float v = (simpp[0 * 64 + tid] + simpp[1 * 64 + tid]) +
                    (simpp[2 * 64 + tid] + simpp[3 * 64 + tid]);
    atomicAdd(&imp[tid], v);
  }
  __syncthreads();

  if (tid == 0) {
    const unsigned old = atomicAdd(cnt, 1u);
    lastflag = (old == 255u) ? 1 : 0;
  }
  __syncthreads();

  if (lastflag && tid < NE) {
    const float v = atomicAdd(&imp[tid], 0.f);   // device-scope read
    float s = v;
#pragma unroll
    for (int d = 1; d < 64; d <<= 1) s += __shfl_xor(s, d);
    const float mean = s / 64.f;
    const float dv = v - mean;
    float sq = dv * dv;
#pragma unroll
    for (int d = 1; d < 64; d <<= 1) sq += __shfl_xor(sq, d);
    const float stdv = sqrtf(sq / 63.f);  // unbiased (E-1)
    const float r = stdv / (mean + 1e-6f);
    if (tid == 0) out[(size_t)NROWS * 4] = r * r;  // d_out[32768]
  }
}

// ---------------------------------------------------------------------------
extern "C" void kernel_launch(void* const* d_in, const int* in_sizes, int n_in,
                              void* d_out, int out_size, void* d_ws, size_t ws_size,
                              hipStream_t stream) {
  const float* x = (const float*)d_in[0];
  const float* W = (const float*)d_in[1];
  float* out  = (float*)d_out;
  _Float16* Whi = (_Float16*)d_ws;                 // 512 KB
  _Float16* Wlo = Whi + (size_t)NE * NK;           // 512 KB
  float* imp  = (float*)(Wlo + (size_t)NE * NK);   // 64 f32
  unsigned* cnt = (unsigned*)(imp + NE);           // 1 u32

  hipLaunchKernelGGL(k_prep,  dim3(1024), dim3(256), 0, stream, W, Whi, Wlo, imp, cnt);
  hipLaunchKernelGGL(k_fused, dim3(256),  dim3(256), 0, stream, x, Whi, Wlo, out, imp, cnt);
}